// Round 10
// baseline (287.979 us; speedup 1.0000x reference)
//
#include <hip/hip_runtime.h>
#include <hip/hip_bf16.h>

// GATNet: 2x GATConv + 2-layer MLP.
// R15 -> R16: wave-autonomous MLP tail in agg2mlp.
//  R15 measured agg2mlp=48.3us vs standalone agg2~39: the post-gather
//  __syncthreads re-introduces degree skew (block waits max-of-16 rows) and
//  the cross-wave reduce barrier holds residency. Now each wave computes the
//  FULL MLP (all 8 j-blocks, K=128) for its own 4 nodes: A-rows dup'd via
//  l15&3, second-layer sum completes in-wave (quad shfl-reduce), no part[].
//  Only barrier = one uniform sync for wm2_s at kernel start (pre-skew).
//  Cost: 4x MFMA issue (0.8us chip-wide), 4x BT3 L2 reads (400MB @35TB/s).
//  - agg1x/conv12/CSR chain: unchanged.

__device__ __forceinline__ float lrelu(float x){ return x > 0.f ? x : 0.2f*x; }
__device__ __forceinline__ float elu_f(float x){ return x > 0.f ? x : __expf(x) - 1.f; }
__device__ __forceinline__ unsigned short f2bf(float f){
  __hip_bfloat16 h = __float2bfloat16(f);   // RNE
  return *reinterpret_cast<unsigned short*>(&h);
}
__device__ __forceinline__ float bflo(unsigned int u){ return __uint_as_float(u << 16); }
__device__ __forceinline__ float bfhi(unsigned int u){ return __uint_as_float(u & 0xffff0000u); }
__device__ __forceinline__ unsigned int packbf(float a, float b){
  return (unsigned int)f2bf(a) | ((unsigned int)f2bf(b) << 16);
}

typedef __attribute__((ext_vector_type(8))) short bf16x8;
typedef __attribute__((ext_vector_type(4))) float f32x4;

// ---------------- prep: va + weight transposes + zero bucket arrays ----------------
__global__ void prep_kernel(const float* __restrict__ W1, unsigned short* __restrict__ BT1a,
                            unsigned short* __restrict__ BT1b,
                            const float* __restrict__ W2, unsigned short* __restrict__ BT2,
                            const float* __restrict__ Wm1, unsigned short* __restrict__ BT3,
                            const float* __restrict__ a1s, const float* __restrict__ a1d,
                            float* __restrict__ va, int* __restrict__ bcount,
                            int* __restrict__ gcur, int NB){
  int idx = blockIdx.x*256 + threadIdx.x;
  const int S1 = 128*256, S2 = 128*256, S3 = 128*128;
  if (idx < S1){
    int k = idx >> 8, c = idx & 255;
    unsigned short v = f2bf(W1[idx]);
    if (c < 128) BT1a[c*128 + k] = v;
    else         BT1b[(c-128)*128 + k] = v;
  } else if (idx < S1 + S2){
    int j = idx - S1;
    int k = j >> 7, n = j & 127;
    BT2[n*256 + k] = f2bf(W2[j]);
  } else if (idx < S1 + S2 + S3){
    int j = idx - S1 - S2;
    int k = j >> 7, n = j & 127;
    BT3[n*128 + k] = f2bf(Wm1[j]);
  } else if (idx < S1 + S2 + S3 + 512){
    int j = idx - S1 - S2 - S3;
    int v = j >> 7, k = j & 127;
    const float* avec = (v < 2) ? a1s : a1d;
    int head = v & 1;
    const float4* wrow = (const float4*)(W1 + (size_t)k*256 + head*128);
    const float4* arow = (const float4*)(avec + head*128);
    float s = 0.f;
    #pragma unroll 8
    for (int f = 0; f < 32; ++f){
      float4 w = wrow[f], a = arow[f];
      s += w.x*a.x + w.y*a.y + w.z*a.z + w.w*a.w;
    }
    va[j] = s;
  } else if (idx < S1 + S2 + S3 + 512 + 2048){
    int z = idx - (S1 + S2 + S3 + 512);
    if (z < 1024){ if (z < NB) bcount[z] = 0; }
    else { z -= 1024; if (z < NB) gcur[z] = 0; }
  }
}

// ---------------- f2bf + conv1 alpha dots + edge histogram (block-role split) ----------------
__global__ __launch_bounds__(256) void f2bf_hist_kernel(
    const float* __restrict__ x, unsigned short* __restrict__ xb, int N,
    const float* __restrict__ va, float* __restrict__ as1, float* __restrict__ ad1,
    const int* __restrict__ dst, int E, int* __restrict__ bcount, int NB, int nbConv)
{
  __shared__ int h[1024];
  if ((int)blockIdx.x < nbConv){
    int i = blockIdx.x*256 + threadIdx.x;
    int total = N*32;
    float4 v = make_float4(0.f,0.f,0.f,0.f);
    if (i < total){
      v = ((const float4*)x)[i];
      ushort4 u; u.x=f2bf(v.x); u.y=f2bf(v.y); u.z=f2bf(v.z); u.w=f2bf(v.w);
      ((ushort4*)xb)[i] = u;
    }
    int c = (i & 31) << 2;
    float4 vs0 = *(const float4*)(va + c);
    float4 vs1 = *(const float4*)(va + 128 + c);
    float4 vd0 = *(const float4*)(va + 256 + c);
    float4 vd1 = *(const float4*)(va + 384 + c);
    float s0 = v.x*vs0.x + v.y*vs0.y + v.z*vs0.z + v.w*vs0.w;
    float s1 = v.x*vs1.x + v.y*vs1.y + v.z*vs1.z + v.w*vs1.w;
    float d0 = v.x*vd0.x + v.y*vd0.y + v.z*vd0.z + v.w*vd0.w;
    float d1 = v.x*vd1.x + v.y*vd1.y + v.z*vd1.z + v.w*vd1.w;
    #pragma unroll
    for (int m = 1; m <= 16; m <<= 1){
      s0 += __shfl_xor(s0, m); s1 += __shfl_xor(s1, m);
      d0 += __shfl_xor(d0, m); d1 += __shfl_xor(d1, m);
    }
    if ((i & 31) == 0 && i < total){
      int n = i >> 5;
      *(float2*)(as1 + 2*n) = make_float2(s0, s1);
      *(float2*)(ad1 + 2*n) = make_float2(d0, d1);
    }
  } else {
    for (int i = threadIdx.x; i < NB; i += 256) h[i] = 0;
    __syncthreads();
    int b0 = blockIdx.x - nbConv;                   // 0..63
    for (int e = b0*256 + threadIdx.x; e < E; e += 64*256)
      atomicAdd(&h[dst[e] >> 6], 1);
    __syncthreads();
    for (int i = threadIdx.x; i < NB; i += 256)
      if (h[i]) atomicAdd(&bcount[i], h[i]);
  }
}

// ---------------- bucketed CSR build: bscatter (with inline scan) + bbuild ----------------
__global__ __launch_bounds__(256) void bscatter_kernel(
    const int* __restrict__ src, const int* __restrict__ dst, int E,
    const int* __restrict__ bcount, int* __restrict__ boff,
    int* __restrict__ gcur, unsigned int* __restrict__ pairs, int NB)
{
  __shared__ int h[1024];
  __shared__ int runbase[1024];
  __shared__ int sc[1024];
  const int t = threadIdx.x;
  const int e0 = blockIdx.x * 4096;

  for (int i = t; i < 1024; i += 256) sc[i] = (i < NB) ? bcount[i] : 0;
  for (int i = t; i < NB; i += 256) h[i] = 0;
  __syncthreads();
  for (int d = 1; d < 1024; d <<= 1){
    int v0 = (t       >= d) ? sc[t       - d] : 0;
    int v1 = (t + 256 >= d) ? sc[t + 256 - d] : 0;
    int v2 = (t + 512 >= d) ? sc[t + 512 - d] : 0;
    int v3 = (t + 768 >= d) ? sc[t + 768 - d] : 0;
    __syncthreads();
    sc[t] += v0; sc[t+256] += v1; sc[t+512] += v2; sc[t+768] += v3;
    __syncthreads();
  }
  if (blockIdx.x == 0){
    for (int i = t; i <= NB; i += 256) boff[i] = i ? sc[i-1] : 0;
  }

  int myb[16]; unsigned int myw[16];
  #pragma unroll
  for (int q = 0; q < 16; ++q){
    int e = e0 + q*256 + t;
    int b = -1; unsigned int w = 0;
    if (e < E){
      int d = dst[e];
      b = d >> 6;
      w = ((unsigned int)(d & 63) << 26) | (unsigned int)src[e];
      atomicAdd(&h[b], 1);
    }
    myb[q] = b; myw[q] = w;
  }
  __syncthreads();
  for (int i = t; i < NB; i += 256)
    runbase[i] = h[i] ? atomicAdd(&gcur[i], h[i]) : 0;
  __syncthreads();
  for (int i = t; i < NB; i += 256) h[i] = 0;
  __syncthreads();
  #pragma unroll
  for (int q = 0; q < 16; ++q){
    if (myb[q] >= 0){
      int off = atomicAdd(&h[myb[q]], 1);
      int base = myb[q] ? sc[myb[q]-1] : 0;
      pairs[(size_t)base + runbase[myb[q]] + off] = myw[q];
    }
  }
}

__global__ __launch_bounds__(256) void bbuild_kernel(
    const unsigned int* __restrict__ pairs, const int* __restrict__ boff,
    int* __restrict__ rowptr, int* __restrict__ csr, int N)
{
  __shared__ int deg[64], offs[64], cur[64];
  const int b = blockIdx.x;
  const int t = threadIdx.x;
  const int n0 = b << 6;
  const int nNodes = min(64, N - n0);
  const int p0 = boff[b], p1 = boff[b+1];
  const int base = p0 + n0;
  if (t < 64) deg[t] = (t < nNodes) ? 1 : 0;
  __syncthreads();
  for (int i = p0 + t; i < p1; i += 256)
    atomicAdd(&deg[pairs[i] >> 26], 1);
  __syncthreads();
  if (t < 64){
    int x = deg[t];
    #pragma unroll
    for (int d = 1; d < 64; d <<= 1){
      int y = __shfl_up(x, d);
      if (t >= d) x += y;
    }
    offs[t] = x - deg[t];
    cur[t] = 1;
    if (t < nNodes){
      rowptr[n0 + t + 1] = base + x;
      csr[base + x - deg[t]] = n0 + t;
    }
    if (b == 0 && t == 0) rowptr[0] = 0;
  }
  __syncthreads();
  for (int i = p0 + t; i < p1; i += 256){
    unsigned int w = pairs[i];
    int dl = w >> 26;
    int s  = (int)(w & 0x03ffffffu);
    int off = atomicAdd(&cur[dl], 1);
    csr[base + offs[dl] + off] = s;
  }
}

// ---------------- fused conv1+conv2 GEMM (R14, unchanged) ----------------
__global__ __launch_bounds__(512, 2) void gemm_conv12_kernel(
    const unsigned short* __restrict__ xa,
    const unsigned short* __restrict__ BT1a, const unsigned short* __restrict__ BT1b,
    const float* __restrict__ b1, const unsigned short* __restrict__ BT2,
    unsigned short* __restrict__ h2b, int M,
    const float* __restrict__ a2s, const float* __restrict__ a2d,
    float* __restrict__ as2, float* __restrict__ ad2)
{
  __shared__ unsigned short t_s[64*264];
  __shared__ unsigned short a_s[64*72];
  __shared__ unsigned short b_s[128*72];
  __shared__ float part_s[64][4];
  __shared__ float part_d[64][4];

  const int tid = threadIdx.x;
  const int lane = tid & 63, wv = tid >> 6;       // 8 waves
  const int l15 = lane & 15, quad = lane >> 4;
  const int r0 = blockIdx.x*64;
  const int mh = (wv & 1)*32;                     // 64 rows -> 2 row-groups
  const int nhp = (wv >> 1)*32;                   // 4 col-groups of 32

  // ---- phase 1: conv1 per head ----
  const int arow = tid >> 3, askc = tid & 7;      // A stage: 64 rows x 8 chunks
  const int brow = tid >> 2, bc2 = (tid & 3)*2;   // B stage: 128 rows x 4 thr (2 chunks each)
  #pragma unroll
  for (int h = 0; h < 2; ++h){
    const unsigned short* BT = h ? BT1b : BT1a;
    f32x4 acc[2][2];
    #pragma unroll
    for (int i = 0; i < 2; ++i)
      #pragma unroll
      for (int j = 0; j < 2; ++j)
        #pragma unroll
        for (int r = 0; r < 4; ++r) acc[i][j][r] = 0.f;

    for (int k0 = 0; k0 < 128; k0 += 64){
      {
        int grow = r0 + arow;
        uint4 v = make_uint4(0u,0u,0u,0u);
        if (grow < M) v = *(const uint4*)(xa + (size_t)grow*256 + h*128 + k0 + askc*8);
        *(uint4*)(&a_s[arow*72 + askc*8]) = v;
      }
      {
        *(uint4*)(&b_s[brow*72 + bc2*8])     = *(const uint4*)(BT + (size_t)brow*128 + k0 + bc2*8);
        *(uint4*)(&b_s[brow*72 + (bc2+1)*8]) = *(const uint4*)(BT + (size_t)brow*128 + k0 + (bc2+1)*8);
      }
      __syncthreads();
      #pragma unroll
      for (int ks = 0; ks < 64; ks += 32){
        bf16x8 af[2], bfr[2];
        #pragma unroll
        for (int i = 0; i < 2; ++i)
          af[i] = *(const bf16x8*)(&a_s[(mh + i*16 + l15)*72 + ks + quad*8]);
        #pragma unroll
        for (int j = 0; j < 2; ++j)
          bfr[j] = *(const bf16x8*)(&b_s[(nhp + j*16 + l15)*72 + ks + quad*8]);
        #pragma unroll
        for (int i = 0; i < 2; ++i)
          #pragma unroll
          for (int j = 0; j < 2; ++j)
            acc[i][j] = __builtin_amdgcn_mfma_f32_16x16x32_bf16(bfr[j], af[i], acc[i][j], 0, 0, 0);
      }
      __syncthreads();
    }
    // T write: elu(acc + bias) -> bf16 LDS
    #pragma unroll
    for (int i = 0; i < 2; ++i){
      int row = mh + i*16 + l15;
      #pragma unroll
      for (int j = 0; j < 2; ++j){
        int n = nhp + j*16 + quad*4;
        float4 bb = *(const float4*)(b1 + h*128 + n);
        ushort4 u;
        u.x = f2bf(elu_f(acc[i][j][0] + bb.x));
        u.y = f2bf(elu_f(acc[i][j][1] + bb.y));
        u.z = f2bf(elu_f(acc[i][j][2] + bb.z));
        u.w = f2bf(elu_f(acc[i][j][3] + bb.w));
        *(ushort4*)(&t_s[row*264 + h*128 + n]) = u;
      }
    }
  }
  __syncthreads();

  // ---- phase 2: conv2, A from t_s (no staging) ----
  f32x4 acc2[2][2];
  #pragma unroll
  for (int i = 0; i < 2; ++i)
    #pragma unroll
    for (int j = 0; j < 2; ++j)
      #pragma unroll
      for (int r = 0; r < 4; ++r) acc2[i][j][r] = 0.f;

  for (int k0 = 0; k0 < 256; k0 += 64){
    {
      *(uint4*)(&b_s[brow*72 + bc2*8])     = *(const uint4*)(BT2 + (size_t)brow*256 + k0 + bc2*8);
      *(uint4*)(&b_s[brow*72 + (bc2+1)*8]) = *(const uint4*)(BT2 + (size_t)brow*256 + k0 + (bc2+1)*8);
    }
    __syncthreads();
    #pragma unroll
    for (int ks = 0; ks < 64; ks += 32){
      bf16x8 af[2], bfr[2];
      #pragma unroll
      for (int i = 0; i < 2; ++i)
        af[i] = *(const bf16x8*)(&t_s[(mh + i*16 + l15)*264 + k0 + ks + quad*8]);
      #pragma unroll
      for (int j = 0; j < 2; ++j)
        bfr[j] = *(const bf16x8*)(&b_s[(nhp + j*16 + l15)*72 + ks + quad*8]);
      #pragma unroll
      for (int i = 0; i < 2; ++i)
        #pragma unroll
        for (int j = 0; j < 2; ++j)
          acc2[i][j] = __builtin_amdgcn_mfma_f32_16x16x32_bf16(bfr[j], af[i], acc2[i][j], 0, 0, 0);
    }
    __syncthreads();
  }

  // ---- epilogue: h2b store + asad2 ----
  #pragma unroll
  for (int i = 0; i < 2; ++i){
    int m = r0 + mh + i*16 + l15;
    float ps = 0.f, pd = 0.f;
    #pragma unroll
    for (int j = 0; j < 2; ++j){
      int n = nhp + j*16 + quad*4;
      float4 wsv = *(const float4*)(a2s + n);
      float4 wdv = *(const float4*)(a2d + n);
      float v0 = acc2[i][j][0], v1 = acc2[i][j][1], v2 = acc2[i][j][2], v3 = acc2[i][j][3];
      ps += v0*wsv.x + v1*wsv.y + v2*wsv.z + v3*wsv.w;
      pd += v0*wdv.x + v1*wdv.y + v2*wdv.z + v3*wdv.w;
      if (m < M){
        ushort4 u;
        u.x = f2bf(v0); u.y = f2bf(v1); u.z = f2bf(v2); u.w = f2bf(v3);
        *(ushort4*)(h2b + (size_t)m*128 + n) = u;
      }
    }
    ps += __shfl_xor(ps, 16); ps += __shfl_xor(ps, 32);
    pd += __shfl_xor(pd, 16); pd += __shfl_xor(pd, 32);
    if (quad == 0){
      part_s[mh + i*16 + l15][wv >> 1] = ps;
      part_d[mh + i*16 + l15][wv >> 1] = pd;
    }
  }
  __syncthreads();
  if (tid < 64){
    int gm = r0 + tid;
    if (gm < M){
      as2[gm] = part_s[tid][0] + part_s[tid][1] + part_s[tid][2] + part_s[tid][3];
      ad2[gm] = part_d[tid][0] + part_d[tid][1] + part_d[tid][2] + part_d[tid][3];
    }
  }
}

// FMA bodies for the aggregation kernels
#define AGG1_FMA(u, a0v, a1v) do{ \
    float f0 = bflo(u.x), f1 = bfhi(u.x), f2v = bflo(u.y), f3 = bfhi(u.y); \
    float f4 = bflo(u.z), f5 = bfhi(u.z), f6 = bflo(u.w), f7 = bfhi(u.w); \
    acc0[0] += a0v*f0; acc0[1] += a0v*f1; acc0[2] += a0v*f2v; acc0[3] += a0v*f3; \
    acc0[4] += a0v*f4; acc0[5] += a0v*f5; acc0[6] += a0v*f6;  acc0[7] += a0v*f7; \
    acc1[0] += a1v*f0; acc1[1] += a1v*f1; acc1[2] += a1v*f2v; acc1[3] += a1v*f3; \
    acc1[4] += a1v*f4; acc1[5] += a1v*f5; acc1[6] += a1v*f6;  acc1[7] += a1v*f7; \
  }while(0)

#define AGG2_FMA(u, av) do{ \
    acc[0] += av*bflo(u.x); acc[1] += av*bfhi(u.x); \
    acc[2] += av*bflo(u.y); acc[3] += av*bfhi(u.y); \
    acc[4] += av*bflo(u.z); acc[5] += av*bfhi(u.z); \
    acc[6] += av*bflo(u.w); acc[7] += av*bfhi(u.w); \
  }while(0)

// ---------------- agg1x: aggregate x rows with 2-head alphas (R13, unchanged) ----------------
__global__ __launch_bounds__(256) void agg1x_kernel(
    const unsigned short* __restrict__ xb, const float* __restrict__ as_,
    const float* __restrict__ ad_, const int* __restrict__ rowptr, const int* __restrict__ csr,
    unsigned short* __restrict__ xa, int N)
{
  const int wv = threadIdx.x >> 6, lane = threadIdx.x & 63;
  const int ql = lane & 15;
  const int n = blockIdx.x*16 + wv*4 + (lane >> 4);
  const bool valid = n < N;
  int start = 0, end = 0;
  float2 adv = make_float2(0.f, 0.f);
  if (valid){ start = rowptr[n]; end = rowptr[n+1]; adv = *(const float2*)(ad_ + 2*n); }

  int jl = start + ql;
  bool have = valid && (jl < end);
  int s_l = 0;
  float p0 = 0.f, p1 = 0.f;
  if (have){
    s_l = csr[jl];
    float2 av = *(const float2*)(as_ + 2*s_l);
    p0 = __expf(lrelu(av.x + adv.x));
    p1 = __expf(lrelu(av.y + adv.y));
  }
  float l0 = p0, l1 = p1;
  for (int j = jl + 16; j < end; j += 16){
    int s = csr[j];
    float2 av = *(const float2*)(as_ + 2*s);
    l0 += __expf(lrelu(av.x + adv.x));
    l1 += __expf(lrelu(av.y + adv.y));
  }
  #pragma unroll
  for (int msk = 1; msk <= 8; msk <<= 1){
    l0 += __shfl_xor(l0, msk);
    l1 += __shfl_xor(l1, msk);
  }
  float inv0 = 1.f / fmaxf(l0, 1e-16f);
  float inv1 = 1.f / fmaxf(l1, 1e-16f);
  float a0_l = p0 * inv0;
  float a1_l = p1 * inv1;

  float acc0[8], acc1[8];
  #pragma unroll
  for (int i = 0; i < 8; ++i){ acc0[i] = 0.f; acc1[i] = 0.f; }
  const int c = ql << 3;
  const unsigned short* hp = xb + c;

  // first <=16 edges: two explicit 8-wide batches (issue 8 loads, then FMA)
  #pragma unroll
  for (int half = 0; half < 2; ++half){
    uint4 u[8]; float b0[8], b1[8];
    #pragma unroll
    for (int t = 0; t < 8; ++t){
      int tt = half*8 + t;
      int sA = __shfl(s_l, tt, 16);
      b0[t] = __shfl(a0_l, tt, 16);
      b1[t] = __shfl(a1_l, tt, 16);
      u[t] = *(const uint4*)(hp + (sA << 7));
    }
    #pragma unroll
    for (int t = 0; t < 8; ++t) AGG1_FMA(u[t], b0[t], b1[t]);
  }
  // remaining edges (deg>16): 2-wide, alpha-masked pairs
  for (int jb = start + 16; jb < end; jb += 16){
    int jl2 = jb + ql;
    int s2 = 0; float a0_2 = 0.f, a1_2 = 0.f;
    if (jl2 < end){
      s2 = csr[jl2];
      float2 av = *(const float2*)(as_ + 2*s2);
      a0_2 = __expf(lrelu(av.x + adv.x)) * inv0;
      a1_2 = __expf(lrelu(av.y + adv.y)) * inv1;
    }
    int cnt2 = min(16, end - jb);
    for (int t2 = 0; t2 < cnt2; t2 += 2){
      int   sA  = __shfl(s2, t2, 16),   sB  = __shfl(s2, t2+1, 16);
      float a0A = __shfl(a0_2, t2, 16), a0B = __shfl(a0_2, t2+1, 16);
      float a1A = __shfl(a1_2, t2, 16), a1B = __shfl(a1_2, t2+1, 16);
      uint4 uA = *(const uint4*)(hp + (sA << 7));
      uint4 uB = *(const uint4*)(hp + (sB << 7));
      AGG1_FMA(uA, a0A, a1A);
      AGG1_FMA(uB, a0B, a1B);
    }
  }

  if (valid){
    uint4 u0, u1;
    u0.x = packbf(acc0[0], acc0[1]); u0.y = packbf(acc0[2], acc0[3]);
    u0.z = packbf(acc0[4], acc0[5]); u0.w = packbf(acc0[6], acc0[7]);
    u1.x = packbf(acc1[0], acc1[1]); u1.y = packbf(acc1[2], acc1[3]);
    u1.z = packbf(acc1[4], acc1[5]); u1.w = packbf(acc1[6], acc1[7]);
    *(uint4*)(xa + (size_t)n*256 + c)       = u0;
    *(uint4*)(xa + (size_t)n*256 + 128 + c) = u1;
  }
}

// ---------------- agg2mlp: conv2 aggregation + MLP, wave-autonomous tail ----------------
// Gather identical to standalone agg2 (16 nodes/block, 1 node per 16-lane
// group). Each wave writes its 4 rows to a wave-private LDS quadrant and runs
// the FULL MLP (8 j-blocks, K=128) for those rows: A-rows dup'd (l15&3),
// layer-2 sum completes in-wave via quad shfl-reduce. No post-gather barrier.
__global__ __launch_bounds__(256, 4) void agg2mlp_kernel(
    const unsigned short* __restrict__ h2b, const float* __restrict__ as_,
    const float* __restrict__ ad_, const int* __restrict__ rowptr, const int* __restrict__ csr,
    const float* __restrict__ b2, const unsigned short* __restrict__ BT3,
    const float* __restrict__ bm1, const float* __restrict__ Wm2,
    const float* __restrict__ bm2, float* __restrict__ out, int N)
{
  __shared__ unsigned short gb_s[4][4*136];   // [wave][row-in-wave][136]
  __shared__ float wm2_s[128*8];
  const int tid = threadIdx.x;
  {
    int i4 = tid*4;
    *(float4*)(&wm2_s[i4]) = *(const float4*)(Wm2 + i4);
  }
  __syncthreads();   // uniform, BEFORE any variable-length work (no skew)

  const int wv = tid >> 6, lane = tid & 63;
  const int ql = lane & 15;
  const int rw = lane >> 4;                 // row-in-wave 0..3
  const int n = blockIdx.x*16 + wv*4 + rw;
  const bool valid = n < N;
  int start = 0, end = 0;
  float adn = 0.f;
  if (valid){ start = rowptr[n]; end = rowptr[n+1]; adn = ad_[n]; }

  int jl = start + ql;
  bool have = valid && (jl < end);
  int s_l = 0;
  float p_l = 0.f;
  if (have){
    s_l = csr[jl];
    p_l = __expf(lrelu(as_[s_l] + adn));
  }
  float l = p_l;
  for (int j = jl + 16; j < end; j += 16)
    l += __expf(lrelu(as_[csr[j]] + adn));
  #pragma unroll
  for (int msk = 1; msk <= 8; msk <<= 1) l += __shfl_xor(l, msk);
  float inv = 1.f / fmaxf(l, 1e-16f);
  float a_l = p_l * inv;

  float acc[8];
  #pragma unroll
  for (int i = 0; i < 8; ++i) acc[i] = 0.f;
  const int c = ql << 3;
  const unsigned short* hp = h2b + c;

  // first <=16 edges: two explicit 8-wide batches
  #pragma unroll
  for (int half = 0; half < 2; ++half){
    uint4 u[8]; float av[8];
    #pragma unroll
    for (int t = 0; t < 8; ++t){
      int tt = half*8 + t;
      int sA = __shfl(s_l, tt, 16);
      av[t] = __shfl(a_l, tt, 16);
      u[t] = *(const uint4*)(hp + (sA << 7));
    }
    #pragma unroll
    for (int t = 0; t < 8; ++t) AGG2_FMA(u[t], av[t]);
  }
  // remaining edges (deg>16)
  for (int jb = start + 16; jb < end; jb += 16){
    int jl2 = jb + ql;
    int s2 = 0; float a2 = 0.f;
    if (jl2 < end){
      s2 = csr[jl2];
      a2 = __expf(lrelu(as_[s2] + adn)) * inv;
    }
    int cnt2 = min(16, end - jb);
    for (int t2 = 0; t2 < cnt2; t2 += 2){
      int   sA = __shfl(s2, t2, 16),  sB = __shfl(s2, t2+1, 16);
      float aA = __shfl(a2, t2, 16),  aB = __shfl(a2, t2+1, 16);
      uint4 uA = *(const uint4*)(hp + (sA << 7));
      uint4 uB = *(const uint4*)(hp + (sB << 7));
      AGG2_FMA(uA, aA);
      AGG2_FMA(uB, aB);
    }
  }

  {
    float4 bb0 = *(const float4*)(b2 + c);
    float4 bb1 = *(const float4*)(b2 + c + 4);
    float o[8];
    o[0]=elu_f(acc[0]+bb0.x); o[1]=elu_f(acc[1]+bb0.y);
    o[2]=elu_f(acc[2]+bb0.z); o[3]=elu_f(acc[3]+bb0.w);
    o[4]=elu_f(acc[4]+bb1.x); o[5]=elu_f(acc[5]+bb1.y);
    o[6]=elu_f(acc[6]+bb1.z); o[7]=elu_f(acc[7]+bb1.w);
    uint4 up;
    up.x = packbf(o[0], o[1]); up.y = packbf(o[2], o[3]);
    up.z = packbf(o[4], o[5]); up.w = packbf(o[6], o[7]);
    *(uint4*)(&gb_s[wv][rw*136 + c]) = up;
  }
  // no barrier: same-wave LDS write->read is in-order; fence the compiler only
  asm volatile("" ::: "memory");

  // ---- MLP tail: this wave's 4 rows, FULL K=128 and all 128 h-cols ----
  const int l15 = lane & 15, quad = lane >> 4;
  const int arow = l15 & 3;                 // rows 4..15 duplicate 0..3
  f32x4 macc[8];
  #pragma unroll
  for (int j = 0; j < 8; ++j)
    #pragma unroll
    for (int r = 0; r < 4; ++r) macc[j][r] = 0.f;

  #pragma unroll
  for (int ks = 0; ks < 128; ks += 32){
    bf16x8 af = *(const bf16x8*)(&gb_s[wv][arow*136 + ks + quad*8]);
    #pragma unroll
    for (int j = 0; j < 8; ++j){
      bf16x8 bfr = *(const bf16x8*)(BT3 + (size_t)(j*16 + l15)*128 + ks + quad*8);
      macc[j] = __builtin_amdgcn_mfma_f32_16x16x32_bf16(bfr, af, macc[j], 0, 0, 0);
    }
  }

  // layer 2: relu(h)@Wm2 -- each lane covers cols {j*16 + quad*4 + r}
  float po[8];
  #pragma unroll
  for (int o = 0; o < 8; ++o) po[o] = 0.f;
  #pragma unroll
  for (int j = 0; j < 8; ++j){
    int nn = j*16 + quad*4;
    float4 bb = *(const float4*)(bm1 + nn);
    #pragma unroll
    for (int r = 0; r < 4; ++r){
      float hcol = fmaxf(macc[j][r] + ((const float*)&bb)[r], 0.f);
      const float* wr = &wm2_s[(nn + r)*8];
      #pragma unroll
      for (int o = 0; o < 8; ++o) po[o] += hcol*wr[o];
    }
  }
  #pragma unroll
  for (int o = 0; o < 8; ++o){
    po[o] += __shfl_xor(po[o], 16);   // reduce over quads (same l15)
    po[o] += __shfl_xor(po[o], 32);
  }
  if (quad == 0 && l15 < 4){
    int gm = blockIdx.x*16 + wv*4 + l15;
    if (gm < N){
      float4 o0, o1;
      o0.x = fmaxf(po[0] + bm2[0], 0.f);
      o0.y = fmaxf(po[1] + bm2[1], 0.f);
      o0.z = fmaxf(po[2] + bm2[2], 0.f);
      o0.w = fmaxf(po[3] + bm2[3], 0.f);
      o1.x = fmaxf(po[4] + bm2[4], 0.f);
      o1.y = fmaxf(po[5] + bm2[5], 0.f);
      o1.z = fmaxf(po[6] + bm2[6], 0.f);
      o1.w = fmaxf(po[7] + bm2[7], 0.f);
      *(float4*)(out + (size_t)gm*8)     = o0;
      *(float4*)(out + (size_t)gm*8 + 4) = o1;
    }
  }
}

extern "C" void kernel_launch(void* const* d_in, const int* in_sizes, int n_in,
                              void* d_out, int out_size, void* d_ws, size_t ws_size,
                              hipStream_t stream)
{
  (void)n_in; (void)out_size; (void)ws_size;
  const float* x   = (const float*)d_in[0];
  const int*   ei  = (const int*)d_in[1];
  const float* W1  = (const float*)d_in[2];
  const float* a1s = (const float*)d_in[3];
  const float* a1d = (const float*)d_in[4];
  const float* b1  = (const float*)d_in[5];
  const float* W2  = (const float*)d_in[6];
  const float* a2s = (const float*)d_in[7];
  const float* a2d = (const float*)d_in[8];
  const float* b2  = (const float*)d_in[9];
  const float* Wm1 = (const float*)d_in[10];
  const float* bm1 = (const float*)d_in[11];
  const float* Wm2 = (const float*)d_in[12];
  const float* bm2 = (const float*)d_in[13];
  float* out = (float*)d_out;

  const int N = in_sizes[0] / 128;
  const int E = in_sizes[1] / 2;
  const int NB = (N + 63) >> 6;
  const int* srcp = ei;
  const int* dstp = ei + E;

  char* ws = (char*)d_ws;
  unsigned short* xb    = (unsigned short*)ws;                       // [N,128] bf16
  unsigned short* xa    = (unsigned short*)(ws + (size_t)N*256);     // [N,256] bf16
  unsigned short* h2b   = (unsigned short*)(ws + (size_t)N*768);     // [N,128] bf16
  char* tail = ws + (size_t)N*1024;
  unsigned short* BT1a = (unsigned short*)tail;
  unsigned short* BT1b = BT1a + 128*128;
  unsigned short* BT2  = BT1b + 128*128;
  unsigned short* BT3  = BT2 + 128*256;
  float* va   = (float*)(BT3 + 128*128);
  float* as1  = va + 512;
  float* ad1  = as1 + (size_t)2*N;
  float* as2  = ad1 + (size_t)2*N;
  float* ad2  = as2 + N;
  int* bcount = (int*)(ad2 + N);
  int* boff   = bcount + 1024;
  int* gcur   = boff + 1032;
  int* rowptr = gcur + 1024;
  int* csr    = rowptr + N + 1;
  unsigned int* pairs = (unsigned int*)(csr + E + N);

  const int nbConv = (N*32 + 255)/256;
  const int prepTotal = 128*256 + 128*256 + 128*128 + 512 + 2048;

  // 1: prep (va + weight transposes + zero bucket arrays)
  prep_kernel<<<(prepTotal + 255)/256, 256, 0, stream>>>(
      W1, BT1a, BT1b, W2, BT2, Wm1, BT3, a1s, a1d, va, bcount, gcur, NB);
  // 2: x convert + conv1 alpha dots + edge histogram
  f2bf_hist_kernel<<<nbConv + 64, 256, 0, stream>>>(x, xb, N, va, as1, ad1,
                                                    dstp, E, bcount, NB, nbConv);
  // 3-4: bucketed CSR (scan folded into bscatter; block 0 publishes boff)
  bscatter_kernel<<<(E + 4095)/4096, 256, 0, stream>>>(srcp, dstp, E, bcount, boff, gcur, pairs, NB);
  bbuild_kernel<<<NB, 256, 0, stream>>>(pairs, boff, rowptr, csr, N);

  const int nb16 = (N + 15) / 16;
  const int g64  = (N + 63) / 64;

  // 5: conv1 aggregation (gathers x)
  agg1x_kernel<<<nb16, 256, 0, stream>>>(xb, as1, ad1, rowptr, csr, xa, N);
  // 6: fused conv1+conv2 projection (+asad2) -> h2b
  gemm_conv12_kernel<<<g64, 512, 0, stream>>>(xa, BT1a, BT1b, b1, BT2,
                                              h2b, N, a2s, a2d, as2, ad2);
  // 7: fused conv2 aggregation + MLP (wave-autonomous tail) -> d_out
  agg2mlp_kernel<<<nb16, 256, 0, stream>>>(h2b, as2, ad2, rowptr, csr,
                                           b2, BT3, bm1, Wm2, bm2, out, N);
}

// Round 11
// 250.018 us; speedup vs baseline: 1.1518x; 1.1518x over previous
//
#include <hip/hip_runtime.h>
#include <hip/hip_bf16.h>

// GATNet: 2x GATConv + 2-layer MLP.
// R17 = revert to R14 (best measured, 251.7us).
//  R16 post-mortem: wave-autonomous MLP tail in agg2mlp regressed 48->90us --
//  duplicating the 32-MFMA + 32x1KB-BT3-read tail across all 4 waves put a
//  serial L2-read chain on every wave's critical path (no role diversity to
//  hide it). R15 showed fused agg2mlp == split agg2+gemm_mlp within noise;
//  R14's split structure measured best. Keeping:
//  - gemm_conv12: fused conv1+conv2 projection (out1b round-trip killed, -11us)
//  - agg1x/agg2: 8-wide explicit gather batches (transaction floor, 5.3TB/s)
//  - bucketed CSR with inline scan (bscan folded into bscatter)
//  - 8 dispatches.

__device__ __forceinline__ float lrelu(float x){ return x > 0.f ? x : 0.2f*x; }
__device__ __forceinline__ float elu_f(float x){ return x > 0.f ? x : __expf(x) - 1.f; }
__device__ __forceinline__ unsigned short f2bf(float f){
  __hip_bfloat16 h = __float2bfloat16(f);   // RNE
  return *reinterpret_cast<unsigned short*>(&h);
}
__device__ __forceinline__ float bflo(unsigned int u){ return __uint_as_float(u << 16); }
__device__ __forceinline__ float bfhi(unsigned int u){ return __uint_as_float(u & 0xffff0000u); }
__device__ __forceinline__ unsigned int packbf(float a, float b){
  return (unsigned int)f2bf(a) | ((unsigned int)f2bf(b) << 16);
}

typedef __attribute__((ext_vector_type(8))) short bf16x8;
typedef __attribute__((ext_vector_type(4))) float f32x4;

// ---------------- prep: va + weight transposes + zero bucket arrays ----------------
__global__ void prep_kernel(const float* __restrict__ W1, unsigned short* __restrict__ BT1a,
                            unsigned short* __restrict__ BT1b,
                            const float* __restrict__ W2, unsigned short* __restrict__ BT2,
                            const float* __restrict__ Wm1, unsigned short* __restrict__ BT3,
                            const float* __restrict__ a1s, const float* __restrict__ a1d,
                            float* __restrict__ va, int* __restrict__ bcount,
                            int* __restrict__ gcur, int NB){
  int idx = blockIdx.x*256 + threadIdx.x;
  const int S1 = 128*256, S2 = 128*256, S3 = 128*128;
  if (idx < S1){
    int k = idx >> 8, c = idx & 255;
    unsigned short v = f2bf(W1[idx]);
    if (c < 128) BT1a[c*128 + k] = v;
    else         BT1b[(c-128)*128 + k] = v;
  } else if (idx < S1 + S2){
    int j = idx - S1;
    int k = j >> 7, n = j & 127;
    BT2[n*256 + k] = f2bf(W2[j]);
  } else if (idx < S1 + S2 + S3){
    int j = idx - S1 - S2;
    int k = j >> 7, n = j & 127;
    BT3[n*128 + k] = f2bf(Wm1[j]);
  } else if (idx < S1 + S2 + S3 + 512){
    int j = idx - S1 - S2 - S3;
    int v = j >> 7, k = j & 127;
    const float* avec = (v < 2) ? a1s : a1d;
    int head = v & 1;
    const float4* wrow = (const float4*)(W1 + (size_t)k*256 + head*128);
    const float4* arow = (const float4*)(avec + head*128);
    float s = 0.f;
    #pragma unroll 8
    for (int f = 0; f < 32; ++f){
      float4 w = wrow[f], a = arow[f];
      s += w.x*a.x + w.y*a.y + w.z*a.z + w.w*a.w;
    }
    va[j] = s;
  } else if (idx < S1 + S2 + S3 + 512 + 2048){
    int z = idx - (S1 + S2 + S3 + 512);
    if (z < 1024){ if (z < NB) bcount[z] = 0; }
    else { z -= 1024; if (z < NB) gcur[z] = 0; }
  }
}

// ---------------- f2bf + conv1 alpha dots + edge histogram (block-role split) ----------------
__global__ __launch_bounds__(256) void f2bf_hist_kernel(
    const float* __restrict__ x, unsigned short* __restrict__ xb, int N,
    const float* __restrict__ va, float* __restrict__ as1, float* __restrict__ ad1,
    const int* __restrict__ dst, int E, int* __restrict__ bcount, int NB, int nbConv)
{
  __shared__ int h[1024];
  if ((int)blockIdx.x < nbConv){
    int i = blockIdx.x*256 + threadIdx.x;
    int total = N*32;
    float4 v = make_float4(0.f,0.f,0.f,0.f);
    if (i < total){
      v = ((const float4*)x)[i];
      ushort4 u; u.x=f2bf(v.x); u.y=f2bf(v.y); u.z=f2bf(v.z); u.w=f2bf(v.w);
      ((ushort4*)xb)[i] = u;
    }
    int c = (i & 31) << 2;
    float4 vs0 = *(const float4*)(va + c);
    float4 vs1 = *(const float4*)(va + 128 + c);
    float4 vd0 = *(const float4*)(va + 256 + c);
    float4 vd1 = *(const float4*)(va + 384 + c);
    float s0 = v.x*vs0.x + v.y*vs0.y + v.z*vs0.z + v.w*vs0.w;
    float s1 = v.x*vs1.x + v.y*vs1.y + v.z*vs1.z + v.w*vs1.w;
    float d0 = v.x*vd0.x + v.y*vd0.y + v.z*vd0.z + v.w*vd0.w;
    float d1 = v.x*vd1.x + v.y*vd1.y + v.z*vd1.z + v.w*vd1.w;
    #pragma unroll
    for (int m = 1; m <= 16; m <<= 1){
      s0 += __shfl_xor(s0, m); s1 += __shfl_xor(s1, m);
      d0 += __shfl_xor(d0, m); d1 += __shfl_xor(d1, m);
    }
    if ((i & 31) == 0 && i < total){
      int n = i >> 5;
      *(float2*)(as1 + 2*n) = make_float2(s0, s1);
      *(float2*)(ad1 + 2*n) = make_float2(d0, d1);
    }
  } else {
    for (int i = threadIdx.x; i < NB; i += 256) h[i] = 0;
    __syncthreads();
    int b0 = blockIdx.x - nbConv;                   // 0..63
    for (int e = b0*256 + threadIdx.x; e < E; e += 64*256)
      atomicAdd(&h[dst[e] >> 6], 1);
    __syncthreads();
    for (int i = threadIdx.x; i < NB; i += 256)
      if (h[i]) atomicAdd(&bcount[i], h[i]);
  }
}

// ---------------- bucketed CSR build: bscatter (with inline scan) + bbuild ----------------
__global__ __launch_bounds__(256) void bscatter_kernel(
    const int* __restrict__ src, const int* __restrict__ dst, int E,
    const int* __restrict__ bcount, int* __restrict__ boff,
    int* __restrict__ gcur, unsigned int* __restrict__ pairs, int NB)
{
  __shared__ int h[1024];
  __shared__ int runbase[1024];
  __shared__ int sc[1024];
  const int t = threadIdx.x;
  const int e0 = blockIdx.x * 4096;

  for (int i = t; i < 1024; i += 256) sc[i] = (i < NB) ? bcount[i] : 0;
  for (int i = t; i < NB; i += 256) h[i] = 0;
  __syncthreads();
  for (int d = 1; d < 1024; d <<= 1){
    int v0 = (t       >= d) ? sc[t       - d] : 0;
    int v1 = (t + 256 >= d) ? sc[t + 256 - d] : 0;
    int v2 = (t + 512 >= d) ? sc[t + 512 - d] : 0;
    int v3 = (t + 768 >= d) ? sc[t + 768 - d] : 0;
    __syncthreads();
    sc[t] += v0; sc[t+256] += v1; sc[t+512] += v2; sc[t+768] += v3;
    __syncthreads();
  }
  if (blockIdx.x == 0){
    for (int i = t; i <= NB; i += 256) boff[i] = i ? sc[i-1] : 0;
  }

  int myb[16]; unsigned int myw[16];
  #pragma unroll
  for (int q = 0; q < 16; ++q){
    int e = e0 + q*256 + t;
    int b = -1; unsigned int w = 0;
    if (e < E){
      int d = dst[e];
      b = d >> 6;
      w = ((unsigned int)(d & 63) << 26) | (unsigned int)src[e];
      atomicAdd(&h[b], 1);
    }
    myb[q] = b; myw[q] = w;
  }
  __syncthreads();
  for (int i = t; i < NB; i += 256)
    runbase[i] = h[i] ? atomicAdd(&gcur[i], h[i]) : 0;
  __syncthreads();
  for (int i = t; i < NB; i += 256) h[i] = 0;
  __syncthreads();
  #pragma unroll
  for (int q = 0; q < 16; ++q){
    if (myb[q] >= 0){
      int off = atomicAdd(&h[myb[q]], 1);
      int base = myb[q] ? sc[myb[q]-1] : 0;
      pairs[(size_t)base + runbase[myb[q]] + off] = myw[q];
    }
  }
}

__global__ __launch_bounds__(256) void bbuild_kernel(
    const unsigned int* __restrict__ pairs, const int* __restrict__ boff,
    int* __restrict__ rowptr, int* __restrict__ csr, int N)
{
  __shared__ int deg[64], offs[64], cur[64];
  const int b = blockIdx.x;
  const int t = threadIdx.x;
  const int n0 = b << 6;
  const int nNodes = min(64, N - n0);
  const int p0 = boff[b], p1 = boff[b+1];
  const int base = p0 + n0;
  if (t < 64) deg[t] = (t < nNodes) ? 1 : 0;
  __syncthreads();
  for (int i = p0 + t; i < p1; i += 256)
    atomicAdd(&deg[pairs[i] >> 26], 1);
  __syncthreads();
  if (t < 64){
    int x = deg[t];
    #pragma unroll
    for (int d = 1; d < 64; d <<= 1){
      int y = __shfl_up(x, d);
      if (t >= d) x += y;
    }
    offs[t] = x - deg[t];
    cur[t] = 1;
    if (t < nNodes){
      rowptr[n0 + t + 1] = base + x;
      csr[base + x - deg[t]] = n0 + t;
    }
    if (b == 0 && t == 0) rowptr[0] = 0;
  }
  __syncthreads();
  for (int i = p0 + t; i < p1; i += 256){
    unsigned int w = pairs[i];
    int dl = w >> 26;
    int s  = (int)(w & 0x03ffffffu);
    int off = atomicAdd(&cur[dl], 1);
    csr[base + offs[dl] + off] = s;
  }
}

// ---------------- GEMM core (mlp only): 128x128 tile, BK=64, bf16 MFMA ----------------
__device__ __forceinline__ void gemm_core(
    const unsigned short* __restrict__ A, int lda,
    const unsigned short* __restrict__ BT, int M, int K, int r0,
    unsigned short* a_s, unsigned short* b_s, f32x4 (&acc)[4][4])
{
  const int tid  = threadIdx.x;
  const int lane = tid & 63, wv = tid >> 6;
  const int mh = (wv & 1)*64, nh = (wv >> 1)*64;
  const int l15 = lane & 15, quad = lane >> 4;
  const int srow = tid >> 3, skc = tid & 7;

  #pragma unroll
  for (int i = 0; i < 4; ++i)
    #pragma unroll
    for (int j = 0; j < 4; ++j)
      #pragma unroll
      for (int r = 0; r < 4; ++r) acc[i][j][r] = 0.f;

  for (int k0 = 0; k0 < K; k0 += 64){
    #pragma unroll
    for (int it = 0; it < 4; ++it){
      int row = it*32 + srow;
      int grow = r0 + row;
      uint4 v = make_uint4(0u,0u,0u,0u);
      if (grow < M) v = *(const uint4*)(A + (size_t)grow*lda + k0 + skc*8);
      *(uint4*)(&a_s[row*72 + skc*8]) = v;
    }
    #pragma unroll
    for (int it = 0; it < 4; ++it){
      int row = it*32 + srow;
      uint4 v = *(const uint4*)(BT + (size_t)row*K + k0 + skc*8);
      *(uint4*)(&b_s[row*72 + skc*8]) = v;
    }
    __syncthreads();
    #pragma unroll
    for (int ks = 0; ks < 64; ks += 32){
      bf16x8 af[4], bfr[4];
      #pragma unroll
      for (int i = 0; i < 4; ++i)
        af[i] = *(const bf16x8*)(&a_s[(mh + i*16 + l15)*72 + ks + quad*8]);
      #pragma unroll
      for (int j = 0; j < 4; ++j)
        bfr[j] = *(const bf16x8*)(&b_s[(nh + j*16 + l15)*72 + ks + quad*8]);
      #pragma unroll
      for (int i = 0; i < 4; ++i)
        #pragma unroll
        for (int j = 0; j < 4; ++j)
          acc[i][j] = __builtin_amdgcn_mfma_f32_16x16x32_bf16(bfr[j], af[i], acc[i][j], 0, 0, 0);
    }
    __syncthreads();
  }
}

// ---------------- fused conv1+conv2 GEMM ----------------
// 64-row tile, 512 thr / 8 waves, 2 blocks/CU.
// Phase1: T = elu(xa@[W1a|W1b]+b1) bf16 -> t_s[64][264].  (K=128, per head)
// Phase2: h2 = T@W2 (K=256), A direct from t_s, B staged from BT2.
// Epilogue: h2b bf16 store + fused asad2 (4-way cross-wave reduce).
__global__ __launch_bounds__(512, 2) void gemm_conv12_kernel(
    const unsigned short* __restrict__ xa,
    const unsigned short* __restrict__ BT1a, const unsigned short* __restrict__ BT1b,
    const float* __restrict__ b1, const unsigned short* __restrict__ BT2,
    unsigned short* __restrict__ h2b, int M,
    const float* __restrict__ a2s, const float* __restrict__ a2d,
    float* __restrict__ as2, float* __restrict__ ad2)
{
  __shared__ unsigned short t_s[64*264];
  __shared__ unsigned short a_s[64*72];
  __shared__ unsigned short b_s[128*72];
  __shared__ float part_s[64][4];
  __shared__ float part_d[64][4];

  const int tid = threadIdx.x;
  const int lane = tid & 63, wv = tid >> 6;       // 8 waves
  const int l15 = lane & 15, quad = lane >> 4;
  const int r0 = blockIdx.x*64;
  const int mh = (wv & 1)*32;                     // 64 rows -> 2 row-groups
  const int nhp = (wv >> 1)*32;                   // 4 col-groups of 32

  // ---- phase 1: conv1 per head ----
  const int arow = tid >> 3, askc = tid & 7;      // A stage: 64 rows x 8 chunks
  const int brow = tid >> 2, bc2 = (tid & 3)*2;   // B stage: 128 rows x 4 thr (2 chunks each)
  #pragma unroll
  for (int h = 0; h < 2; ++h){
    const unsigned short* BT = h ? BT1b : BT1a;
    f32x4 acc[2][2];
    #pragma unroll
    for (int i = 0; i < 2; ++i)
      #pragma unroll
      for (int j = 0; j < 2; ++j)
        #pragma unroll
        for (int r = 0; r < 4; ++r) acc[i][j][r] = 0.f;

    for (int k0 = 0; k0 < 128; k0 += 64){
      {
        int grow = r0 + arow;
        uint4 v = make_uint4(0u,0u,0u,0u);
        if (grow < M) v = *(const uint4*)(xa + (size_t)grow*256 + h*128 + k0 + askc*8);
        *(uint4*)(&a_s[arow*72 + askc*8]) = v;
      }
      {
        *(uint4*)(&b_s[brow*72 + bc2*8])     = *(const uint4*)(BT + (size_t)brow*128 + k0 + bc2*8);
        *(uint4*)(&b_s[brow*72 + (bc2+1)*8]) = *(const uint4*)(BT + (size_t)brow*128 + k0 + (bc2+1)*8);
      }
      __syncthreads();
      #pragma unroll
      for (int ks = 0; ks < 64; ks += 32){
        bf16x8 af[2], bfr[2];
        #pragma unroll
        for (int i = 0; i < 2; ++i)
          af[i] = *(const bf16x8*)(&a_s[(mh + i*16 + l15)*72 + ks + quad*8]);
        #pragma unroll
        for (int j = 0; j < 2; ++j)
          bfr[j] = *(const bf16x8*)(&b_s[(nhp + j*16 + l15)*72 + ks + quad*8]);
        #pragma unroll
        for (int i = 0; i < 2; ++i)
          #pragma unroll
          for (int j = 0; j < 2; ++j)
            acc[i][j] = __builtin_amdgcn_mfma_f32_16x16x32_bf16(bfr[j], af[i], acc[i][j], 0, 0, 0);
      }
      __syncthreads();
    }
    // T write: elu(acc + bias) -> bf16 LDS
    #pragma unroll
    for (int i = 0; i < 2; ++i){
      int row = mh + i*16 + l15;
      #pragma unroll
      for (int j = 0; j < 2; ++j){
        int n = nhp + j*16 + quad*4;
        float4 bb = *(const float4*)(b1 + h*128 + n);
        ushort4 u;
        u.x = f2bf(elu_f(acc[i][j][0] + bb.x));
        u.y = f2bf(elu_f(acc[i][j][1] + bb.y));
        u.z = f2bf(elu_f(acc[i][j][2] + bb.z));
        u.w = f2bf(elu_f(acc[i][j][3] + bb.w));
        *(ushort4*)(&t_s[row*264 + h*128 + n]) = u;
      }
    }
  }
  __syncthreads();

  // ---- phase 2: conv2, A from t_s (no staging) ----
  f32x4 acc2[2][2];
  #pragma unroll
  for (int i = 0; i < 2; ++i)
    #pragma unroll
    for (int j = 0; j < 2; ++j)
      #pragma unroll
      for (int r = 0; r < 4; ++r) acc2[i][j][r] = 0.f;

  for (int k0 = 0; k0 < 256; k0 += 64){
    {
      *(uint4*)(&b_s[brow*72 + bc2*8])     = *(const uint4*)(BT2 + (size_t)brow*256 + k0 + bc2*8);
      *(uint4*)(&b_s[brow*72 + (bc2+1)*8]) = *(const uint4*)(BT2 + (size_t)brow*256 + k0 + (bc2+1)*8);
    }
    __syncthreads();
    #pragma unroll
    for (int ks = 0; ks < 64; ks += 32){
      bf16x8 af[2], bfr[2];
      #pragma unroll
      for (int i = 0; i < 2; ++i)
        af[i] = *(const bf16x8*)(&t_s[(mh + i*16 + l15)*264 + k0 + ks + quad*8]);
      #pragma unroll
      for (int j = 0; j < 2; ++j)
        bfr[j] = *(const bf16x8*)(&b_s[(nhp + j*16 + l15)*72 + ks + quad*8]);
      #pragma unroll
      for (int i = 0; i < 2; ++i)
        #pragma unroll
        for (int j = 0; j < 2; ++j)
          acc2[i][j] = __builtin_amdgcn_mfma_f32_16x16x32_bf16(bfr[j], af[i], acc2[i][j], 0, 0, 0);
    }
    __syncthreads();
  }

  // ---- epilogue: h2b store + asad2 ----
  #pragma unroll
  for (int i = 0; i < 2; ++i){
    int m = r0 + mh + i*16 + l15;
    float ps = 0.f, pd = 0.f;
    #pragma unroll
    for (int j = 0; j < 2; ++j){
      int n = nhp + j*16 + quad*4;
      float4 wsv = *(const float4*)(a2s + n);
      float4 wdv = *(const float4*)(a2d + n);
      float v0 = acc2[i][j][0], v1 = acc2[i][j][1], v2 = acc2[i][j][2], v3 = acc2[i][j][3];
      ps += v0*wsv.x + v1*wsv.y + v2*wsv.z + v3*wsv.w;
      pd += v0*wdv.x + v1*wdv.y + v2*wdv.z + v3*wdv.w;
      if (m < M){
        ushort4 u;
        u.x = f2bf(v0); u.y = f2bf(v1); u.z = f2bf(v2); u.w = f2bf(v3);
        *(ushort4*)(h2b + (size_t)m*128 + n) = u;
      }
    }
    ps += __shfl_xor(ps, 16); ps += __shfl_xor(ps, 32);
    pd += __shfl_xor(pd, 16); pd += __shfl_xor(pd, 32);
    if (quad == 0){
      part_s[mh + i*16 + l15][wv >> 1] = ps;
      part_d[mh + i*16 + l15][wv >> 1] = pd;
    }
  }
  __syncthreads();
  if (tid < 64){
    int gm = r0 + tid;
    if (gm < M){
      as2[gm] = part_s[tid][0] + part_s[tid][1] + part_s[tid][2] + part_s[tid][3];
      ad2[gm] = part_d[tid][0] + part_d[tid][1] + part_d[tid][2] + part_d[tid][3];
    }
  }
}

// ---------------- MLP GEMM: relu(gb@Wm1+bm1) then fused @Wm2+bm2,relu -> d_out ----------------
__global__ __launch_bounds__(256) void gemm_mlp_kernel(
    const unsigned short* __restrict__ gb, const unsigned short* __restrict__ BT3,
    int M, const float* __restrict__ bm1, const float* __restrict__ Wm2,
    const float* __restrict__ bm2, float* __restrict__ out)
{
  __shared__ unsigned short a_s[128*72];
  __shared__ unsigned short b_s[128*72];
  __shared__ float wm2_s[128*8];
  __shared__ float part[128][2][8];
  const int tid = threadIdx.x;
  {
    int i4 = tid*4;                 // 1024 floats, 4 per thread
    *(float4*)(&wm2_s[i4]) = *(const float4*)(Wm2 + i4);
  }
  const int r0 = blockIdx.y*128;
  f32x4 acc[4][4];
  gemm_core(gb, 128, BT3, M, 128, r0, a_s, b_s, acc);

  const int lane = tid & 63, wv = tid >> 6;
  const int mh = (wv & 1)*64, nh = (wv >> 1)*64;
  const int l15 = lane & 15, quad = lane >> 4;
  #pragma unroll
  for (int i = 0; i < 4; ++i){
    float po[8];
    #pragma unroll
    for (int o = 0; o < 8; ++o) po[o] = 0.f;
    #pragma unroll
    for (int j = 0; j < 4; ++j){
      int n = nh + j*16 + quad*4;
      float4 bb = *(const float4*)(bm1 + n);
      #pragma unroll
      for (int r = 0; r < 4; ++r){
        float hcol = fmaxf(acc[i][j][r] + ((const float*)&bb)[r], 0.f);
        const float* wr = &wm2_s[(n + r)*8];
        #pragma unroll
        for (int o = 0; o < 8; ++o) po[o] += hcol*wr[o];
      }
    }
    #pragma unroll
    for (int o = 0; o < 8; ++o){
      po[o] += __shfl_xor(po[o], 16);
      po[o] += __shfl_xor(po[o], 32);
    }
    if (quad == 0){
      #pragma unroll
      for (int o = 0; o < 8; ++o) part[mh + i*16 + l15][wv >> 1][o] = po[o];
    }
  }
  __syncthreads();
  if (tid < 128){
    int gm = r0 + tid;
    if (gm < M){
      float4 o0, o1;
      o0.x = fmaxf(part[tid][0][0] + part[tid][1][0] + bm2[0], 0.f);
      o0.y = fmaxf(part[tid][0][1] + part[tid][1][1] + bm2[1], 0.f);
      o0.z = fmaxf(part[tid][0][2] + part[tid][1][2] + bm2[2], 0.f);
      o0.w = fmaxf(part[tid][0][3] + part[tid][1][3] + bm2[3], 0.f);
      o1.x = fmaxf(part[tid][0][4] + part[tid][1][4] + bm2[4], 0.f);
      o1.y = fmaxf(part[tid][0][5] + part[tid][1][5] + bm2[5], 0.f);
      o1.z = fmaxf(part[tid][0][6] + part[tid][1][6] + bm2[6], 0.f);
      o1.w = fmaxf(part[tid][0][7] + part[tid][1][7] + bm2[7], 0.f);
      *(float4*)(out + (size_t)gm*8)     = o0;
      *(float4*)(out + (size_t)gm*8 + 4) = o1;
    }
  }
}

// FMA bodies for the aggregation kernels
#define AGG1_FMA(u, a0v, a1v) do{ \
    float f0 = bflo(u.x), f1 = bfhi(u.x), f2v = bflo(u.y), f3 = bfhi(u.y); \
    float f4 = bflo(u.z), f5 = bfhi(u.z), f6 = bflo(u.w), f7 = bfhi(u.w); \
    acc0[0] += a0v*f0; acc0[1] += a0v*f1; acc0[2] += a0v*f2v; acc0[3] += a0v*f3; \
    acc0[4] += a0v*f4; acc0[5] += a0v*f5; acc0[6] += a0v*f6;  acc0[7] += a0v*f7; \
    acc1[0] += a1v*f0; acc1[1] += a1v*f1; acc1[2] += a1v*f2v; acc1[3] += a1v*f3; \
    acc1[4] += a1v*f4; acc1[5] += a1v*f5; acc1[6] += a1v*f6;  acc1[7] += a1v*f7; \
  }while(0)

#define AGG2_FMA(u, av) do{ \
    acc[0] += av*bflo(u.x); acc[1] += av*bfhi(u.x); \
    acc[2] += av*bflo(u.y); acc[3] += av*bfhi(u.y); \
    acc[4] += av*bflo(u.z); acc[5] += av*bfhi(u.z); \
    acc[6] += av*bflo(u.w); acc[7] += av*bfhi(u.w); \
  }while(0)

// ---------------- agg1x: aggregate x rows with 2-head alphas ----------------
__global__ __launch_bounds__(256) void agg1x_kernel(
    const unsigned short* __restrict__ xb, const float* __restrict__ as_,
    const float* __restrict__ ad_, const int* __restrict__ rowptr, const int* __restrict__ csr,
    unsigned short* __restrict__ xa, int N)
{
  const int wv = threadIdx.x >> 6, lane = threadIdx.x & 63;
  const int ql = lane & 15;
  const int n = blockIdx.x*16 + wv*4 + (lane >> 4);
  const bool valid = n < N;
  int start = 0, end = 0;
  float2 adv = make_float2(0.f, 0.f);
  if (valid){ start = rowptr[n]; end = rowptr[n+1]; adv = *(const float2*)(ad_ + 2*n); }

  int jl = start + ql;
  bool have = valid && (jl < end);
  int s_l = 0;
  float p0 = 0.f, p1 = 0.f;
  if (have){
    s_l = csr[jl];
    float2 av = *(const float2*)(as_ + 2*s_l);
    p0 = __expf(lrelu(av.x + adv.x));
    p1 = __expf(lrelu(av.y + adv.y));
  }
  float l0 = p0, l1 = p1;
  for (int j = jl + 16; j < end; j += 16){
    int s = csr[j];
    float2 av = *(const float2*)(as_ + 2*s);
    l0 += __expf(lrelu(av.x + adv.x));
    l1 += __expf(lrelu(av.y + adv.y));
  }
  #pragma unroll
  for (int msk = 1; msk <= 8; msk <<= 1){
    l0 += __shfl_xor(l0, msk);
    l1 += __shfl_xor(l1, msk);
  }
  float inv0 = 1.f / fmaxf(l0, 1e-16f);
  float inv1 = 1.f / fmaxf(l1, 1e-16f);
  float a0_l = p0 * inv0;
  float a1_l = p1 * inv1;

  float acc0[8], acc1[8];
  #pragma unroll
  for (int i = 0; i < 8; ++i){ acc0[i] = 0.f; acc1[i] = 0.f; }
  const int c = ql << 3;
  const unsigned short* hp = xb + c;

  // first <=16 edges: two explicit 8-wide batches (issue 8 loads, then FMA)
  #pragma unroll
  for (int half = 0; half < 2; ++half){
    uint4 u[8]; float b0[8], b1[8];
    #pragma unroll
    for (int t = 0; t < 8; ++t){
      int tt = half*8 + t;
      int sA = __shfl(s_l, tt, 16);
      b0[t] = __shfl(a0_l, tt, 16);
      b1[t] = __shfl(a1_l, tt, 16);
      u[t] = *(const uint4*)(hp + (sA << 7));
    }
    #pragma unroll
    for (int t = 0; t < 8; ++t) AGG1_FMA(u[t], b0[t], b1[t]);
  }
  // remaining edges (deg>16): 2-wide, alpha-masked pairs
  for (int jb = start + 16; jb < end; jb += 16){
    int jl2 = jb + ql;
    int s2 = 0; float a0_2 = 0.f, a1_2 = 0.f;
    if (jl2 < end){
      s2 = csr[jl2];
      float2 av = *(const float2*)(as_ + 2*s2);
      a0_2 = __expf(lrelu(av.x + adv.x)) * inv0;
      a1_2 = __expf(lrelu(av.y + adv.y)) * inv1;
    }
    int cnt2 = min(16, end - jb);
    for (int t2 = 0; t2 < cnt2; t2 += 2){
      int   sA  = __shfl(s2, t2, 16),   sB  = __shfl(s2, t2+1, 16);
      float a0A = __shfl(a0_2, t2, 16), a0B = __shfl(a0_2, t2+1, 16);
      float a1A = __shfl(a1_2, t2, 16), a1B = __shfl(a1_2, t2+1, 16);
      uint4 uA = *(const uint4*)(hp + (sA << 7));
      uint4 uB = *(const uint4*)(hp + (sB << 7));
      AGG1_FMA(uA, a0A, a1A);
      AGG1_FMA(uB, a0B, a1B);
    }
  }

  if (valid){
    uint4 u0, u1;
    u0.x = packbf(acc0[0], acc0[1]); u0.y = packbf(acc0[2], acc0[3]);
    u0.z = packbf(acc0[4], acc0[5]); u0.w = packbf(acc0[6], acc0[7]);
    u1.x = packbf(acc1[0], acc1[1]); u1.y = packbf(acc1[2], acc1[3]);
    u1.z = packbf(acc1[4], acc1[5]); u1.w = packbf(acc1[6], acc1[7]);
    *(uint4*)(xa + (size_t)n*256 + c)       = u0;
    *(uint4*)(xa + (size_t)n*256 + 128 + c) = u1;
  }
}

// ---------------- agg2: 4 nodes/wave, 16 lanes/node ----------------
__global__ __launch_bounds__(256) void agg2_kernel(
    const unsigned short* __restrict__ h2b, const float* __restrict__ as_,
    const float* __restrict__ ad_, const int* __restrict__ rowptr, const int* __restrict__ csr,
    const float* __restrict__ b2, unsigned short* __restrict__ outb, int N)
{
  const int wv = threadIdx.x >> 6, lane = threadIdx.x & 63;
  const int ql = lane & 15;
  const int n = blockIdx.x*16 + wv*4 + (lane >> 4);
  const bool valid = n < N;
  int start = 0, end = 0;
  float adn = 0.f;
  if (valid){ start = rowptr[n]; end = rowptr[n+1]; adn = ad_[n]; }

  int jl = start + ql;
  bool have = valid && (jl < end);
  int s_l = 0;
  float p_l = 0.f;
  if (have){
    s_l = csr[jl];
    p_l = __expf(lrelu(as_[s_l] + adn));
  }
  float l = p_l;
  for (int j = jl + 16; j < end; j += 16)
    l += __expf(lrelu(as_[csr[j]] + adn));
  #pragma unroll
  for (int msk = 1; msk <= 8; msk <<= 1) l += __shfl_xor(l, msk);
  float inv = 1.f / fmaxf(l, 1e-16f);
  float a_l = p_l * inv;

  float acc[8];
  #pragma unroll
  for (int i = 0; i < 8; ++i) acc[i] = 0.f;
  const int c = ql << 3;
  const unsigned short* hp = h2b + c;

  // first <=16 edges: two explicit 8-wide batches
  #pragma unroll
  for (int half = 0; half < 2; ++half){
    uint4 u[8]; float av[8];
    #pragma unroll
    for (int t = 0; t < 8; ++t){
      int tt = half*8 + t;
      int sA = __shfl(s_l, tt, 16);
      av[t] = __shfl(a_l, tt, 16);
      u[t] = *(const uint4*)(hp + (sA << 7));
    }
    #pragma unroll
    for (int t = 0; t < 8; ++t) AGG2_FMA(u[t], av[t]);
  }
  // remaining edges (deg>16)
  for (int jb = start + 16; jb < end; jb += 16){
    int jl2 = jb + ql;
    int s2 = 0; float a2 = 0.f;
    if (jl2 < end){
      s2 = csr[jl2];
      a2 = __expf(lrelu(as_[s2] + adn)) * inv;
    }
    int cnt2 = min(16, end - jb);
    for (int t2 = 0; t2 < cnt2; t2 += 2){
      int   sA = __shfl(s2, t2, 16),  sB = __shfl(s2, t2+1, 16);
      float aA = __shfl(a2, t2, 16),  aB = __shfl(a2, t2+1, 16);
      uint4 uA = *(const uint4*)(hp + (sA << 7));
      uint4 uB = *(const uint4*)(hp + (sB << 7));
      AGG2_FMA(uA, aA);
      AGG2_FMA(uB, aB);
    }
  }

  if (valid){
    float4 bb0 = *(const float4*)(b2 + c);
    float4 bb1 = *(const float4*)(b2 + c + 4);
    float o[8];
    o[0]=elu_f(acc[0]+bb0.x); o[1]=elu_f(acc[1]+bb0.y);
    o[2]=elu_f(acc[2]+bb0.z); o[3]=elu_f(acc[3]+bb0.w);
    o[4]=elu_f(acc[4]+bb1.x); o[5]=elu_f(acc[5]+bb1.y);
    o[6]=elu_f(acc[6]+bb1.z); o[7]=elu_f(acc[7]+bb1.w);
    uint4 up;
    up.x = packbf(o[0], o[1]); up.y = packbf(o[2], o[3]);
    up.z = packbf(o[4], o[5]); up.w = packbf(o[6], o[7]);
    *(uint4*)(outb + (size_t)n*128 + c) = up;
  }
}

extern "C" void kernel_launch(void* const* d_in, const int* in_sizes, int n_in,
                              void* d_out, int out_size, void* d_ws, size_t ws_size,
                              hipStream_t stream)
{
  (void)n_in; (void)out_size; (void)ws_size;
  const float* x   = (const float*)d_in[0];
  const int*   ei  = (const int*)d_in[1];
  const float* W1  = (const float*)d_in[2];
  const float* a1s = (const float*)d_in[3];
  const float* a1d = (const float*)d_in[4];
  const float* b1  = (const float*)d_in[5];
  const float* W2  = (const float*)d_in[6];
  const float* a2s = (const float*)d_in[7];
  const float* a2d = (const float*)d_in[8];
  const float* b2  = (const float*)d_in[9];
  const float* Wm1 = (const float*)d_in[10];
  const float* bm1 = (const float*)d_in[11];
  const float* Wm2 = (const float*)d_in[12];
  const float* bm2 = (const float*)d_in[13];
  float* out = (float*)d_out;

  const int N = in_sizes[0] / 128;
  const int E = in_sizes[1] / 2;
  const int NB = (N + 63) >> 6;
  const int* srcp = ei;
  const int* dstp = ei + E;

  char* ws = (char*)d_ws;
  unsigned short* xb    = (unsigned short*)ws;                       // [N,128] bf16 -> gb later
  unsigned short* xa    = (unsigned short*)(ws + (size_t)N*256);     // [N,256] bf16
  unsigned short* h2b   = (unsigned short*)(ws + (size_t)N*768);     // [N,128] bf16
  char* tail = ws + (size_t)N*1024;
  unsigned short* BT1a = (unsigned short*)tail;
  unsigned short* BT1b = BT1a + 128*128;
  unsigned short* BT2  = BT1b + 128*128;
  unsigned short* BT3  = BT2 + 128*256;
  float* va   = (float*)(BT3 + 128*128);
  float* as1  = va + 512;
  float* ad1  = as1 + (size_t)2*N;
  float* as2  = ad1 + (size_t)2*N;
  float* ad2  = as2 + N;
  int* bcount = (int*)(ad2 + N);
  int* boff   = bcount + 1024;
  int* gcur   = boff + 1032;
  int* rowptr = gcur + 1024;
  int* csr    = rowptr + N + 1;
  unsigned int* pairs = (unsigned int*)(csr + E + N);

  unsigned short* gb = xb;            // xb dead after agg1x

  const int nbConv = (N*32 + 255)/256;
  const int prepTotal = 128*256 + 128*256 + 128*128 + 512 + 2048;

  // 1: prep (va + weight transposes + zero bucket arrays)
  prep_kernel<<<(prepTotal + 255)/256, 256, 0, stream>>>(
      W1, BT1a, BT1b, W2, BT2, Wm1, BT3, a1s, a1d, va, bcount, gcur, NB);
  // 2: x convert + conv1 alpha dots + edge histogram
  f2bf_hist_kernel<<<nbConv + 64, 256, 0, stream>>>(x, xb, N, va, as1, ad1,
                                                    dstp, E, bcount, NB, nbConv);
  // 3-4: bucketed CSR (scan folded into bscatter; block 0 publishes boff)
  bscatter_kernel<<<(E + 4095)/4096, 256, 0, stream>>>(srcp, dstp, E, bcount, boff, gcur, pairs, NB);
  bbuild_kernel<<<NB, 256, 0, stream>>>(pairs, boff, rowptr, csr, N);

  const int nb16 = (N + 15) / 16;
  const int g64  = (N + 63) / 64;
  const int gy   = (N + 127) / 128;

  // 5: conv1 aggregation (gathers x)
  agg1x_kernel<<<nb16, 256, 0, stream>>>(xb, as1, ad1, rowptr, csr, xa, N);
  // 6: fused conv1+conv2 projection (+asad2) -> h2b
  gemm_conv12_kernel<<<g64, 512, 0, stream>>>(xa, BT1a, BT1b, b1, BT2,
                                              h2b, N, a2s, a2d, as2, ad2);
  // 7: conv2 aggregation
  agg2_kernel<<<nb16, 256, 0, stream>>>(h2b, as2, ad2, rowptr, csr, b2, gb, N);
  // 8: MLP (gemm + fused second layer) -> d_out
  gemm_mlp_kernel<<<dim3(1, gy), 256, 0, stream>>>(gb, BT3, N, bm1, Wm2, bm2, out);
}